// Round 14
// baseline (426.535 us; speedup 1.0000x reference)
//
#include <hip/hip_runtime.h>

// Problem constants (match reference)
constexpr int Bn = 32;      // batch
constexpr int Nn = 512;     // logical qubits
constexpr int Qq = 512;     // physical qubits
constexpr int Ee = 4096;    // edges per batch
constexpr int Mtot = Bn * Nn;  // 16384 rows of P_flat
constexpr int ZCAP = 512;   // edges per 32-row chunk (avg 256, >15 sigma safe)
constexpr int ZP = 520;     // padded LDS row stride (f32) for k_zbuild

typedef short bf16x8 __attribute__((ext_vector_type(8)));
typedef float f32x4 __attribute__((ext_vector_type(4)));
typedef unsigned short u16;
typedef unsigned short u16x8 __attribute__((ext_vector_type(8)));
typedef unsigned int u32;

__device__ inline u16 f2bf(float f) {   // RNE float->bf16
    union { float f; unsigned u; } x; x.f = f;
    unsigned r = x.u + 0x7FFFu + ((x.u >> 16) & 1u);
    return (u16)(r >> 16);
}
__device__ inline void gload_lds16(const u16* g, u16* l) {
    __builtin_amdgcn_global_load_lds(
        (const __attribute__((address_space(1))) unsigned int*)g,
        (__attribute__((address_space(3))) unsigned int*)l, 16, 0, 0);
}
__device__ inline u16x8 cast8(float4 v0, float4 v1) {
    u16x8 o;
    o[0] = f2bf(v0.x); o[1] = f2bf(v0.y); o[2] = f2bf(v0.z); o[3] = f2bf(v0.w);
    o[4] = f2bf(v1.x); o[5] = f2bf(v1.y); o[6] = f2bf(v1.z); o[7] = f2bf(v1.w);
    return o;
}

// ---------------------------------------------------------------------------
// Kernel 1: blocks 0..31  -> inv_w[b] (+ out[0]=0 on block 0)
//           blocks 32..287 -> Dbf = bf16(3*max(d_hw-1,0))
// ---------------------------------------------------------------------------
__global__ __launch_bounds__(256) void k_init(const float* __restrict__ edge_w,
                                              const float* __restrict__ d_hw,
                                              float* __restrict__ inv_w,
                                              u16* __restrict__ Dbf,
                                              float* __restrict__ out) {
    if (blockIdx.x < 32) {
        int b = blockIdx.x;
        const float* w = edge_w + (size_t)b * Ee;
        float s = 0.f;
        for (int i = threadIdx.x; i < Ee; i += 256) s += w[i];
        for (int off = 32; off; off >>= 1) s += __shfl_down(s, off);
        __shared__ float red[4];
        int wave = threadIdx.x >> 6, lane = threadIdx.x & 63;
        if (lane == 0) red[wave] = s;
        __syncthreads();
        if (threadIdx.x == 0) {
            float t = red[0] + red[1] + red[2] + red[3];
            inv_w[b] = 1.0f / fmaxf(t, 1e-8f);
            if (b == 0) out[0] = 0.f;
        }
    } else {
        int i = (blockIdx.x - 32) * 256 + threadIdx.x;   // 4 elems per thread
        float4 v = ((const float4*)d_hw)[i];
        ushort4 o;
        o.x = f2bf(3.f * fmaxf(v.x - 1.f, 0.f));
        o.y = f2bf(3.f * fmaxf(v.y - 1.f, 0.f));
        o.z = f2bf(3.f * fmaxf(v.z - 1.f, 0.f));
        o.w = f2bf(3.f * fmaxf(v.w - 1.f, 0.f));
        ((ushort4*)Dbf)[i] = o;
    }
}

// ---------------------------------------------------------------------------
// Kernel 2: Z-build.  Z[b*512+s][:] = sum_{e: src=s} w_e * P[b, dst_e, :]
//   One block per (batch bb, 32-row chunk ch): scans the batch's 4096 edges,
//   keeps those with s>>5 == ch (LDS compaction), then wave-per-edge
//   accumulation into an LDS f32 chunk via native ds_add_f32 (atomicAdd on
//   shared float; no read-back chain). Column map lane+64k -> 2-way bank
//   aliasing only (free). Chunk written out coalesced as f32.
// ---------------------------------------------------------------------------
__global__ __launch_bounds__(256) void k_zbuild(const float* __restrict__ P,
                                                const int* __restrict__ esrc,
                                                const int* __restrict__ edst,
                                                const float* __restrict__ ew,
                                                float* __restrict__ Z) {
    __shared__ float z[32 * ZP];          // 66.6 KB accumulation chunk
    __shared__ u32 list[ZCAP];
    __shared__ float wlist[ZCAP];
    __shared__ u32 lcnt;

    const int tid = threadIdx.x;
    const int lane = tid & 63;
    const int wave = tid >> 6;
    const int bb = blockIdx.x >> 4;       // batch
    const int ch = blockIdx.x & 15;       // 32-row chunk within batch

    // zero the chunk
    for (int i = tid; i < 32 * ZP; i += 256) z[i] = 0.f;
    if (tid == 0) lcnt = 0;
    __syncthreads();

    // scan & filter this batch's edges
    const int base = bb * Ee;
    for (int i = tid; i < Ee; i += 256) {
        int s = esrc[base + i];
        if ((s >> 5) == ch) {
            int d = edst[base + i];
            float wt = ew[base + i];
            u32 pos = atomicAdd(&lcnt, 1u);
            if (pos < ZCAP) {
                list[pos] = ((u32)(s & 31) << 9) | (u32)d;
                wlist[pos] = wt;
            }
        }
    }
    __syncthreads();

    // wave-per-edge accumulate: z[row][lane + 64k] += w * P[b,d][lane + 64k]
    const float* Pb = P + (size_t)bb * Nn * Qq;
    int cnt = min((int)lcnt, ZCAP);
    for (int i = wave; i < cnt; i += 4) {
        u32 e = list[i];
        float wt = wlist[i];
        int row = e >> 9, d = (int)(e & 511);
        const float* pr = Pb + (size_t)d * Qq + lane;
        float* zr = &z[row * ZP + lane];
        #pragma unroll
        for (int k = 0; k < 8; ++k)
            atomicAdd(zr + k * 64, wt * pr[k * 64]);
    }
    __syncthreads();

    // write chunk: rows [bb*512 + ch*32, +32) of Z
    float* Zb = Z + ((size_t)bb * Nn + ch * 32) * Qq;
    for (int i = tid; i < 32 * 128; i += 256) {
        int r = i >> 7, cb = i & 127;
        float4 v = *(const float4*)&z[r * ZP + cb * 4];
        *(float4*)&Zb[(size_t)r * Qq + cb * 4] = v;
    }
}

// ---------------------------------------------------------------------------
// Kernel 3: fused cast+GEMM1+dot:  G = bf16(P) * D^T (D symmetric), then
//   instead of writing G: local += acc * Z[row][col], block-reduce, one
//   atomicAdd(out) per block. r7's proven 2-barrier core: BM=64, BN=128,
//   BK=32, 4 waves 2x2, acc[2][4]; A reg-staged f32->bf16, B global_load_lds.
//   1D grid 1024 + bijective XCD-chunk swizzle.
// ---------------------------------------------------------------------------
__global__ __launch_bounds__(256) void k_gemm1z(const float* __restrict__ P,
                                                const u16* __restrict__ Dbf,
                                                const float* __restrict__ Z,
                                                const float* __restrict__ inv_w,
                                                float* __restrict__ out) {
    __shared__ u16 As[64 * 32];    // 4 KB
    __shared__ u16 Bs[128 * 32];   // 8 KB
    __shared__ float red[4];
    const int tid = threadIdx.x;
    const int lane = tid & 63;
    const int wave = tid >> 6;
    const int wm = wave >> 1, wn = wave & 1;

    int t = (blockIdx.x & 7) * 128 + (blockIdx.x >> 3);
    int xt = t & 3, yt = t >> 2;        // consecutive t share yt (A-panel)
    const int M0 = yt * 64, N0 = xt * 128;
    const int bb = M0 >> 9;             // batch of this 64-row panel

    const int srow = tid >> 2;            // 0..63
    const int scol = (tid & 3) * 8;

    const float* gA = P + (size_t)(M0 + srow) * Qq + scol;
    const u16* gB = Dbf + (size_t)(N0 + srow) * Qq + scol;

    u16* lA = As + srow * 32 + scol;      // linear, = tid*16 bytes
    u16* lB0 = Bs + wave * 512;           // rows 0..63
    u16* lB1 = Bs + 2048 + wave * 512;    // rows 64..127

    f32x4 acc[2][4] = {};

    for (int k0 = 0; k0 < Qq; k0 += 32) {
        gload_lds16(gB + k0, lB0);
        gload_lds16(gB + (size_t)64 * Qq + k0, lB1);
        float4 v0 = *(const float4*)(gA + k0);
        float4 v1 = *(const float4*)(gA + k0 + 4);
        *(u16x8*)lA = cast8(v0, v1);
        __syncthreads();

        bf16x8 a[2], b[4];
        #pragma unroll
        for (int mi = 0; mi < 2; ++mi)
            a[mi] = *(const bf16x8*)&As[(wm * 32 + mi * 16 + (lane & 15)) * 32 + (lane >> 4) * 8];
        #pragma unroll
        for (int ni = 0; ni < 4; ++ni)
            b[ni] = *(const bf16x8*)&Bs[(wn * 64 + ni * 16 + (lane & 15)) * 32 + (lane >> 4) * 8];
        #pragma unroll
        for (int mi = 0; mi < 2; ++mi)
            #pragma unroll
            for (int ni = 0; ni < 4; ++ni)
                acc[mi][ni] = __builtin_amdgcn_mfma_f32_16x16x32_bf16(a[mi], b[ni], acc[mi][ni], 0, 0, 0);
        __syncthreads();
    }

    // epilogue: dot acc (= G tile, f32) against Z tile; no G write.
    // C/D layout: col=lane&15, row=(lane>>4)*4+r  [guide m89]
    const int r0 = (lane >> 4) * 4;
    const int c = lane & 15;
    const float* Zt = Z + (size_t)M0 * Qq + N0;
    float local = 0.f;
    #pragma unroll
    for (int mi = 0; mi < 2; ++mi) {
        #pragma unroll
        for (int ni = 0; ni < 4; ++ni) {
            int row = wm * 32 + mi * 16 + r0;
            int col = wn * 64 + ni * 16 + c;
            #pragma unroll
            for (int r = 0; r < 4; ++r)
                local += acc[mi][ni][r] * Zt[(size_t)(row + r) * Qq + col];
        }
    }
    for (int off = 32; off; off >>= 1) local += __shfl_down(local, off);
    if (lane == 0) red[wave] = local;
    __syncthreads();
    if (tid == 0)
        atomicAdd(out, (red[0] + red[1] + red[2] + red[3]) * inv_w[bb] * (1.0f / Bn));
}

// ---------------------------------------------------------------------------
extern "C" void kernel_launch(void* const* d_in, const int* in_sizes, int n_in,
                              void* d_out, int out_size, void* d_ws, size_t ws_size,
                              hipStream_t stream) {
    const float* P    = (const float*)d_in[0];   // [B,N,Q] f32
    const float* d_hw = (const float*)d_in[1];   // [Q,Q]   f32
    const int* esrc   = (const int*)d_in[2];     // [B,E]
    const int* edst   = (const int*)d_in[3];     // [B,E]
    const float* ew   = (const float*)d_in[4];   // [B,E]
    float* out = (float*)d_out;

    char* ws = (char*)d_ws;
    float* inv_w = (float*)ws;                    // 32 f32
    u16* Dbf = (u16*)(ws + 1024);                 // [512][512] bf16, 0.52 MB
    float* Z = (float*)(ws + 2 * 1024 * 1024);    // [Mtot][512] f32, 33.55 MB

    k_init<<<dim3(288), dim3(256), 0, stream>>>(ew, d_hw, inv_w, Dbf, out);
    k_zbuild<<<dim3(512), dim3(256), 0, stream>>>(P, esrc, edst, ew, Z);
    k_gemm1z<<<dim3(1024), dim3(256), 0, stream>>>(P, Dbf, Z, inv_w, out);
}

// Round 15
// 55.695 us; speedup vs baseline: 7.6585x; 7.6585x over previous
//
#include <hip/hip_runtime.h>

// Problem constants (match reference)
constexpr int Bn = 32;      // batch
constexpr int Nn = 512;     // logical qubits
constexpr int Qq = 512;     // physical qubits
constexpr int Ee = 4096;    // edges per batch
constexpr int Mtot = Bn * Nn;  // 16384 rows of P_flat

typedef short bf16x8 __attribute__((ext_vector_type(8)));
typedef float f32x4 __attribute__((ext_vector_type(4)));
typedef unsigned short u16;
typedef unsigned short u16x8 __attribute__((ext_vector_type(8)));

__device__ inline u16 f2bf(float f) {   // RNE float->bf16
    union { float f; unsigned u; } x; x.f = f;
    unsigned r = x.u + 0x7FFFu + ((x.u >> 16) & 1u);
    return (u16)(r >> 16);
}
__device__ inline float bf2f(u16 h) {
    union { unsigned u; float f; } x; x.u = ((unsigned)h) << 16;
    return x.f;
}
__device__ inline void gload_lds16(const u16* g, u16* l) {
    __builtin_amdgcn_global_load_lds(
        (const __attribute__((address_space(1))) unsigned int*)g,
        (__attribute__((address_space(3))) unsigned int*)l, 16, 0, 0);
}
__device__ inline u16x8 cast8(float4 v0, float4 v1) {
    u16x8 o;
    o[0] = f2bf(v0.x); o[1] = f2bf(v0.y); o[2] = f2bf(v0.z); o[3] = f2bf(v0.w);
    o[4] = f2bf(v1.x); o[5] = f2bf(v1.y); o[6] = f2bf(v1.z); o[7] = f2bf(v1.w);
    return o;
}

// ---------------------------------------------------------------------------
// Kernel 1 (merged): blocks 0..31  -> inv_w[b] (+ out[0]=0 on block 0)
//                    blocks 32..287 -> Dbf = bf16(3*max(d_hw-1,0))
// ---------------------------------------------------------------------------
__global__ __launch_bounds__(256) void k_init(const float* __restrict__ edge_w,
                                              const float* __restrict__ d_hw,
                                              float* __restrict__ inv_w,
                                              u16* __restrict__ Dbf,
                                              float* __restrict__ out) {
    if (blockIdx.x < 32) {
        int b = blockIdx.x;
        const float* w = edge_w + (size_t)b * Ee;
        float s = 0.f;
        for (int i = threadIdx.x; i < Ee; i += 256) s += w[i];
        for (int off = 32; off; off >>= 1) s += __shfl_down(s, off);
        __shared__ float red[4];
        int wave = threadIdx.x >> 6, lane = threadIdx.x & 63;
        if (lane == 0) red[wave] = s;
        __syncthreads();
        if (threadIdx.x == 0) {
            float t = red[0] + red[1] + red[2] + red[3];
            inv_w[b] = 1.0f / fmaxf(t, 1e-8f);
            if (b == 0) out[0] = 0.f;
        }
    } else {
        int i = (blockIdx.x - 32) * 256 + threadIdx.x;   // 4 elems per thread
        float4 v = ((const float4*)d_hw)[i];
        ushort4 o;
        o.x = f2bf(3.f * fmaxf(v.x - 1.f, 0.f));
        o.y = f2bf(3.f * fmaxf(v.y - 1.f, 0.f));
        o.z = f2bf(3.f * fmaxf(v.z - 1.f, 0.f));
        o.w = f2bf(3.f * fmaxf(v.w - 1.f, 0.f));
        ((ushort4*)Dbf)[i] = o;
    }
}

// ---------------------------------------------------------------------------
// Kernel 2: fused cast+GEMM1:  G = bf16(P) * D^T  (D symmetric).
//   r7 structure, single change: BK 32 -> 64 (8 K-steps, half the barrier
//   pairs). BM=64, BN=128, 4 waves in 2x2, acc[2][4]; 2 MFMA sub-steps/iter.
//   A reg-staged f32->bf16 (2 passes of 32 rows); B via global_load_lds
//   (4 passes of 32 rows). N0==0 blocks publish bf16 A to Pbf.
//   1D grid 1024 + bijective XCD-chunk swizzle. LDS 8K + 16K = 24 KB.
// ---------------------------------------------------------------------------
__global__ __launch_bounds__(256) void k_gemm1(const float* __restrict__ P,
                                               const u16* __restrict__ Dbf,
                                               u16* __restrict__ Pbf,
                                               u16* __restrict__ G) {
    __shared__ u16 As[64 * 64];     //  8 KB
    __shared__ u16 Bs[128 * 64];    // 16 KB
    const int tid = threadIdx.x;
    const int lane = tid & 63;
    const int wave = tid >> 6;
    const int wm = wave >> 1, wn = wave & 1;

    int t = (blockIdx.x & 7) * 128 + (blockIdx.x >> 3);
    int xt = t & 3, yt = t >> 2;        // consecutive t share yt (A-panel)
    const int M0 = yt * 64, N0 = xt * 128;

    // staging geometry: 16B per thread per pass; pass covers 32 rows x 128B
    const int srow = tid >> 3;            // 0..31
    const int scol = (tid & 7) * 8;       // shorts (and f32 offset below)

    const float* gA = P + (size_t)(M0 + srow) * Qq + scol;
    const u16* gB = Dbf + (size_t)(N0 + srow) * Qq + scol;
    u16* pOut = Pbf + (size_t)(M0 + srow) * Qq + scol;

    f32x4 acc[2][4] = {};

    for (int k0 = 0; k0 < Qq; k0 += 64) {
        // B: 4 gload passes (rows p*32 + srow), linear LDS dest
        #pragma unroll
        for (int p = 0; p < 4; ++p)
            gload_lds16(gB + (size_t)(p * 32) * Qq + k0,
                        Bs + p * 2048 + wave * 512);
        // A: 2 reg-cast passes (rows p*32 + srow)
        #pragma unroll
        for (int p = 0; p < 2; ++p) {
            const float* src = gA + (size_t)(p * 32) * Qq + k0;
            float4 v0 = *(const float4*)src;
            float4 v1 = *(const float4*)(src + 4);
            u16x8 o = cast8(v0, v1);
            *(u16x8*)&As[(p * 32 + srow) * 64 + scol] = o;
            if (N0 == 0) *(u16x8*)(pOut + (size_t)(p * 32) * Qq + k0) = o;
        }
        __syncthreads();

        #pragma unroll
        for (int kk = 0; kk < 2; ++kk) {
            bf16x8 a[2], b[4];
            #pragma unroll
            for (int mi = 0; mi < 2; ++mi)
                a[mi] = *(const bf16x8*)&As[(wm * 32 + mi * 16 + (lane & 15)) * 64 + kk * 32 + (lane >> 4) * 8];
            #pragma unroll
            for (int ni = 0; ni < 4; ++ni)
                b[ni] = *(const bf16x8*)&Bs[(wn * 64 + ni * 16 + (lane & 15)) * 64 + kk * 32 + (lane >> 4) * 8];
            #pragma unroll
            for (int mi = 0; mi < 2; ++mi)
                #pragma unroll
                for (int ni = 0; ni < 4; ++ni)
                    acc[mi][ni] = __builtin_amdgcn_mfma_f32_16x16x32_bf16(a[mi], b[ni], acc[mi][ni], 0, 0, 0);
        }
        __syncthreads();
    }

    // epilogue: C/D layout col=lane&15, row=(lane>>4)*4+r  [guide m89]
    const int r0 = (lane >> 4) * 4;
    const int c = lane & 15;
    #pragma unroll
    for (int mi = 0; mi < 2; ++mi) {
        #pragma unroll
        for (int ni = 0; ni < 4; ++ni) {
            int row = M0 + wm * 32 + mi * 16 + r0;
            int col = N0 + wn * 64 + ni * 16 + c;
            #pragma unroll
            for (int r = 0; r < 4; ++r)
                G[(size_t)(row + r) * Qq + col] = f2bf(acc[mi][ni][r]);
        }
    }
}

// ---------------------------------------------------------------------------
// Kernel 3: GEMM2  S_b = G_b * P_b^T  (symmetric -> lower-triangle tiles).
//   r7 structure, BK 32 -> 64. Both operands via global_load_lds
//   (A: 2 passes, B: 4 passes of 32 rows). 640 blocks, XCD-chunk swizzle.
// ---------------------------------------------------------------------------
__global__ __launch_bounds__(256) void k_gemm2(const u16* __restrict__ A,
                                               const u16* __restrict__ Bt,
                                               u16* __restrict__ C) {
    __shared__ u16 As[64 * 64];     //  8 KB
    __shared__ u16 Bs[128 * 64];    // 16 KB
    const int tid = threadIdx.x;
    const int lane = tid & 63;
    const int wave = tid >> 6;
    const int wm = wave >> 1, wn = wave & 1;

    int t = (blockIdx.x & 7) * 80 + (blockIdx.x >> 3);   // nwg=640=8*80
    int bb = t / 20, tt = t % 20;
    int nt = (tt < 8) ? 0 : (tt < 14) ? 1 : (tt < 18) ? 2 : 3;
    int mt = (tt < 8) ? tt : (tt < 14) ? tt - 6 : (tt < 18) ? tt - 10 : tt - 12;
    const int M0 = bb * 512 + mt * 64, N0 = nt * 128;
    const u16* Bbase = Bt + (size_t)bb * Nn * Qq;

    const int srow = tid >> 3;            // 0..31
    const int scol = (tid & 7) * 8;

    const u16* gA = A + (size_t)(M0 + srow) * Qq + scol;
    const u16* gB = Bbase + (size_t)(N0 + srow) * Qq + scol;

    f32x4 acc[2][4] = {};

    for (int k0 = 0; k0 < Qq; k0 += 64) {
        #pragma unroll
        for (int p = 0; p < 2; ++p)
            gload_lds16(gA + (size_t)(p * 32) * Qq + k0,
                        As + p * 2048 + wave * 512);
        #pragma unroll
        for (int p = 0; p < 4; ++p)
            gload_lds16(gB + (size_t)(p * 32) * Qq + k0,
                        Bs + p * 2048 + wave * 512);
        __syncthreads();

        #pragma unroll
        for (int kk = 0; kk < 2; ++kk) {
            bf16x8 a[2], b[4];
            #pragma unroll
            for (int mi = 0; mi < 2; ++mi)
                a[mi] = *(const bf16x8*)&As[(wm * 32 + mi * 16 + (lane & 15)) * 64 + kk * 32 + (lane >> 4) * 8];
            #pragma unroll
            for (int ni = 0; ni < 4; ++ni)
                b[ni] = *(const bf16x8*)&Bs[(wn * 64 + ni * 16 + (lane & 15)) * 64 + kk * 32 + (lane >> 4) * 8];
            #pragma unroll
            for (int mi = 0; mi < 2; ++mi)
                #pragma unroll
                for (int ni = 0; ni < 4; ++ni)
                    acc[mi][ni] = __builtin_amdgcn_mfma_f32_16x16x32_bf16(a[mi], b[ni], acc[mi][ni], 0, 0, 0);
        }
        __syncthreads();
    }

    const int r0 = (lane >> 4) * 4;
    const int c = lane & 15;
    u16* Crow = C + (size_t)M0 * Qq;
    #pragma unroll
    for (int mi = 0; mi < 2; ++mi) {
        #pragma unroll
        for (int ni = 0; ni < 4; ++ni) {
            int row = wm * 32 + mi * 16 + r0;
            int col = N0 + wn * 64 + ni * 16 + c;
            #pragma unroll
            for (int r = 0; r < 4; ++r)
                Crow[(size_t)(row + r) * Qq + col] = f2bf(acc[mi][ni][r]);
        }
    }
}

// ---------------------------------------------------------------------------
// Kernel 4: out += sum_e w_e * S[b, max(s,d), min(s,d)] * inv_w[b] / B
// ---------------------------------------------------------------------------
__global__ __launch_bounds__(256) void k_lookup(const u16* __restrict__ S,
                                                const int* __restrict__ esrc,
                                                const int* __restrict__ edst,
                                                const float* __restrict__ ew,
                                                const float* __restrict__ inv_w,
                                                float* __restrict__ out) {
    int idx = blockIdx.x * 256 + threadIdx.x;   // 0 .. B*E-1
    int b = idx >> 12;                          // / 4096
    int s = esrc[idx];
    int d = edst[idx];
    int hi = max(s, d), lo = min(s, d);
    float w = ew[idx] * inv_w[b];
    float val = bf2f(S[((size_t)b << 18) + ((size_t)hi << 9) + (size_t)lo]);
    float local = w * val;
    for (int off = 32; off; off >>= 1) local += __shfl_down(local, off);
    __shared__ float red[4];
    int wave = threadIdx.x >> 6, lane = threadIdx.x & 63;
    if (lane == 0) red[wave] = local;
    __syncthreads();
    if (threadIdx.x == 0)
        atomicAdd(out, (red[0] + red[1] + red[2] + red[3]) * (1.0f / Bn));
}

// ---------------------------------------------------------------------------
extern "C" void kernel_launch(void* const* d_in, const int* in_sizes, int n_in,
                              void* d_out, int out_size, void* d_ws, size_t ws_size,
                              hipStream_t stream) {
    const float* P    = (const float*)d_in[0];   // [B,N,Q] f32
    const float* d_hw = (const float*)d_in[1];   // [Q,Q]   f32
    const int* esrc   = (const int*)d_in[2];     // [B,E]
    const int* edst   = (const int*)d_in[3];     // [B,E]
    const float* ew   = (const float*)d_in[4];   // [B,E]
    float* out = (float*)d_out;

    char* ws = (char*)d_ws;
    float* inv_w = (float*)ws;                          // 32 f32 (1 KB reserved)
    u16* Pbf = (u16*)(ws + 1024);                       // [Mtot][512] bf16, 16.78 MB
    u16* Dbf = Pbf + (size_t)Mtot * Qq;                 // [512][512]  bf16, 0.52 MB
    u16* G   = Dbf + (size_t)Qq * Qq;                   // [Mtot][512] bf16, 16.78 MB
    u16* S   = G + (size_t)Mtot * Qq;                   // [B][512][512] bf16, 16.78 MB

    k_init<<<dim3(288), dim3(256), 0, stream>>>(ew, d_hw, inv_w, Dbf, out);
    k_gemm1<<<dim3(1024), dim3(256), 0, stream>>>(P, Dbf, Pbf, G);
    k_gemm2<<<dim3(640), dim3(256), 0, stream>>>(G, Pbf, S);
    k_lookup<<<dim3((Bn * Ee) / 256), dim3(256), 0, stream>>>(
        S, esrc, edst, ew, inv_w, out);
}